// Round 5
// baseline (58447.845 us; speedup 1.0000x reference)
//
#include <hip/hip_runtime.h>
#include <cstdint>

#define TT 256
#define HH 256
#define LL 3
#define NTH 1024
#define LN_EPS 1e-5f

// ---------------- helpers ----------------

__device__ __forceinline__ float fast_sigmoid(float x) {
    return 1.f / (1.f + __expf(-x));
}
__device__ __forceinline__ float fast_tanh(float x) {
    float xc = fminf(fmaxf(x, -15.f), 15.f);
    float e = __expf(2.f * xc);
    return 1.f - 2.f / (e + 1.f);
}
__device__ __forceinline__ float relu(float x) { return fmaxf(x, 0.f); }

// Per-row dual reduction. Threads are (n = tid&255, r = tid>>8); each row r
// occupies waves 4r..4r+3. Sums a,b over the 256 threads of each row.
// scr needs 32 floats. Callers must ping-pong scr between consecutive calls.
__device__ __forceinline__ float2 red2row(float a, float b, float* scr, int tid) {
#pragma unroll
    for (int o = 32; o > 0; o >>= 1) {
        a += __shfl_down(a, o);
        b += __shfl_down(b, o);
    }
    int w = (tid >> 6) & 3;
    int r = tid >> 8;
    if ((tid & 63) == 0) { scr[r * 8 + w] = a; scr[r * 8 + 4 + w] = b; }
    __syncthreads();
    float s = 0.f, s2 = 0.f;
#pragma unroll
    for (int i = 0; i < 4; i++) { s += scr[r * 8 + i]; s2 += scr[r * 8 + 4 + i]; }
    return make_float2(s, s2);
}

// Head dual reduction: threads t<512 are (m = t&127, r = t>>7); each row = 2
// waves. Threads >=512 must pass a=b=0 (their wave leaders don't write).
__device__ __forceinline__ float2 red2head(float a, float b, float* scr, int tid) {
#pragma unroll
    for (int o = 32; o > 0; o >>= 1) {
        a += __shfl_down(a, o);
        b += __shfl_down(b, o);
    }
    int w = tid >> 6;
    if ((tid & 63) == 0 && w < 8) { scr[w] = a; scr[16 + w] = b; }
    __syncthreads();
    int r = (tid >> 7) & 3;
    return make_float2(scr[2 * r] + scr[2 * r + 1], scr[16 + 2 * r] + scr[16 + 2 * r + 1]);
}

// 4-row matvec: dst[((g*4+r)*N + n] = sum_{k in group g} xT[k][r] * W[k][n].
// W fp32 row-major [K,N] read as float4 (one 16B load feeds 16 FMAs).
// xT is LDS [K][4] (float4 per k, broadcast read). nQ*G must equal 1024.
template <int K, int N, int G>
__device__ __forceinline__ void matvecR(const float* __restrict__ Wp,
                                        const float* __restrict__ xT,
                                        float* __restrict__ dst, int t) {
    constexpr int nQ = N / 4;
    constexpr int kc = K / G;
    static_assert(nQ * G == NTH, "bad split");
    int g = t / nQ;
    int j = t - g * nQ;
    const float4* Wq = (const float4*)Wp + (size_t)(g * kc) * nQ + j;
    const float4* xq = (const float4*)xT + g * kc;
    float4 a0 = {0,0,0,0}, a1 = {0,0,0,0}, a2 = {0,0,0,0}, a3 = {0,0,0,0};
#pragma unroll 8
    for (int k = 0; k < kc; k++) {
        float4 w = Wq[(size_t)k * nQ];
        float4 x = xq[k];
        a0.x = fmaf(w.x, x.x, a0.x); a0.y = fmaf(w.y, x.x, a0.y);
        a0.z = fmaf(w.z, x.x, a0.z); a0.w = fmaf(w.w, x.x, a0.w);
        a1.x = fmaf(w.x, x.y, a1.x); a1.y = fmaf(w.y, x.y, a1.y);
        a1.z = fmaf(w.z, x.y, a1.z); a1.w = fmaf(w.w, x.y, a1.w);
        a2.x = fmaf(w.x, x.z, a2.x); a2.y = fmaf(w.y, x.z, a2.y);
        a2.z = fmaf(w.z, x.z, a2.z); a2.w = fmaf(w.w, x.z, a2.w);
        a3.x = fmaf(w.x, x.w, a3.x); a3.y = fmaf(w.y, x.w, a3.y);
        a3.z = fmaf(w.z, x.w, a3.z); a3.w = fmaf(w.w, x.w, a3.w);
    }
    float4* dq = (float4*)dst;
    dq[(g * 4 + 0) * nQ + j] = a0;
    dq[(g * 4 + 1) * nQ + j] = a1;
    dq[(g * 4 + 2) * nQ + j] = a2;
    dq[(g * 4 + 3) * nQ + j] = a3;
}

// ---------------- main kernel ----------------

struct Args {
    const float *params, *disp;
    const float *embed_b, *embed_g, *embed_beta;
    const float *skip_b;
    const float *gates_b;
    const float *inln_g, *inln_b, *hln_g, *hln_b, *sln_g, *sln_b;
    const float *ab1, *aw2, *ab2;
    const float *rb1, *rb2, *rln_g, *rln_b;
    const float *ob1, *oln_g, *oln_b, *ow2, *ob2;
    const float *gw, *a1w, *r1w, *r2w, *ew, *sw, *o1w;
    float* out;
};

__global__ __launch_bounds__(NTH) void xlstm_kernel(Args A) {
    const int tid = threadIdx.x;
    const int blk = blockIdx.x;          // rows 4*blk .. 4*blk+3
    const int n = tid & 255;             // neuron
    const int r = tid >> 8;              // row slot 0..3

    __shared__ __align__(16) float g4[16384];    // 64 KB matvec partials
    __shared__ __align__(16) float bufT[512 * 4]; // xnhn_T / r1out_T  [k][4]
    __shared__ __align__(16) float cT[256 * 4];   // c_prev transposed
    __shared__ __align__(16) float hT[256 * 4];   // h transposed
    __shared__ __align__(16) float yT[384 * 4];   // head input transposed
    __shared__ float skv[4 * 128];                // skip activations [r][m]
    __shared__ __align__(16) float xtT[17 * 4];   // input features [k][r]
    __shared__ float scrA[40], scrB[40];          // reduction scratch (ping-pong)

    // per-(neuron,row) state in registers
    float xr = 0.f;
    float hreg[LL] = {0.f, 0.f, 0.f};
    float creg[LL] = {0.f, 0.f, 0.f};

    int rp = 0;
    auto RED = [&](float a, float b) {
        float2 res = red2row(a, b, (rp & 1) ? scrB : scrA, tid);
        rp++;
        return res;
    };
    auto REDH = [&](float a, float b) {
        float2 res = red2head(a, b, (rp & 1) ? scrB : scrA, tid);
        rp++;
        return res;
    };

    // stage constant params once: xtT[1+k][rr]
    if (tid < 64) {
        int k = tid >> 2, rr = tid & 3;
        xtT[(1 + k) * 4 + rr] = A.params[(4 * blk + rr) * 16 + k];
    }
    __syncthreads();

    for (int t = 0; t < TT; t++) {
        if (tid < 4) xtT[tid] = A.disp[(4 * blk + tid) * TT + t];
        __syncthreads();   // xtT ready; also fences prev-step LDS reuse

        // ---- embed: ev[r][n] ----
        float ev = A.embed_b[n];
#pragma unroll
        for (int k = 0; k < 17; k++) ev = fmaf(A.ew[k * 256 + n], xtT[k * 4 + r], ev);

        // ---- skip (threads 0..511): skv[r2][m] ----
        if (tid < 512) {
            int m = tid & 127, r2 = tid >> 7;
            float s = A.skip_b[m];
#pragma unroll
            for (int k = 0; k < 17; k++) s = fmaf(A.sw[k * 128 + m], xtT[k * 4 + r2], s);
            skv[r2 * 128 + m] = relu(s);
        }

        float2 f2 = RED(ev, ev * ev);
        float mu = f2.x / HH;
        float inv = rsqrtf(f2.y / HH - mu * mu + LN_EPS);
        xr = relu((ev - mu) * inv * A.embed_g[n] + A.embed_beta[n]);

#pragma unroll
        for (int l = 0; l < LL; l++) {
            // ---- xn = LN(x), hn = LN(h); stage bufT (transposed) + cT ----
            f2 = RED(xr, xr * xr);
            mu = f2.x / HH; inv = rsqrtf(f2.y / HH - mu * mu + LN_EPS);
            bufT[n * 4 + r] = (xr - mu) * inv * A.inln_g[l * HH + n] + A.inln_b[l * HH + n];
            float hv = hreg[l];
            f2 = RED(hv, hv * hv);
            mu = f2.x / HH; inv = rsqrtf(f2.y / HH - mu * mu + LN_EPS);
            bufT[(256 + n) * 4 + r] = (hv - mu) * inv * A.hln_g[l * HH + n] + A.hln_b[l * HH + n];
            cT[n * 4 + r] = creg[l];
            __syncthreads();

            // ---- imp = sigmoid(tanh(c @ aw1 + ab1) @ aw2 + ab2) ----
            matvecR<256, 256, 16>(A.a1w + (size_t)l * (256 * 256), cT, g4, tid);
            __syncthreads();
            float s = A.ab1[l * HH + n];
#pragma unroll
            for (int g = 0; g < 16; g++) s += g4[(g * 4 + r) * 256 + n];
            float v = fast_tanh(s) * A.aw2[l * HH + n];
            f2 = RED(v, 0.f);                       // barrier frees g4 for gates
            float impv = fast_sigmoid(f2.x + A.ab2[l]);

            // ---- gates = [xn,hn] @ gates_w ----
            matvecR<512, 1024, 4>(A.gw + (size_t)l * (512 * 1024), bufT, g4, tid);
            __syncthreads();
            const float* gb = A.gates_b + l * 1024;
            float si = gb[n], sf = gb[256 + n], sg = gb[512 + n], so = gb[768 + n];
#pragma unroll
            for (int g = 0; g < 4; g++) {
                si += g4[(g * 4 + r) * 1024 + n];
                sf += g4[(g * 4 + r) * 1024 + 256 + n];
                sg += g4[(g * 4 + r) * 1024 + 512 + n];
                so += g4[(g * 4 + r) * 1024 + 768 + n];
            }
            float og = fast_sigmoid(so);
            v = (fast_sigmoid(sf) * creg[l] + fast_sigmoid(si) * fast_tanh(sg)) * impv;
            f2 = RED(v, v * v);
            mu = f2.x / HH; inv = rsqrtf(f2.y / HH - mu * mu + LN_EPS);
            float cn = (v - mu) * inv * A.sln_g[l * HH + n] + A.sln_b[l * HH + n];
            creg[l] = cn;
            float hn = og * fast_tanh(cn);
            hreg[l] = hn;
            hT[n * 4 + r] = hn;
            __syncthreads();

            // ---- residual MLP ----
            matvecR<256, 512, 8>(A.r1w + (size_t)l * (256 * 512), hT, g4, tid);
            __syncthreads();
            {
                int m = tid & 511, rr = tid >> 9;    // rows rr and rr+2
#pragma unroll
                for (int p = 0; p < 2; p++) {
                    int r2 = rr + 2 * p;
                    float ss = A.rb1[l * 512 + m];
#pragma unroll
                    for (int g = 0; g < 8; g++) ss += g4[(g * 4 + r2) * 512 + m];
                    bufT[m * 4 + r2] = relu(ss);
                }
            }
            __syncthreads();

            matvecR<512, 256, 16>(A.r2w + (size_t)l * (512 * 256), bufT, g4, tid);
            __syncthreads();
            s = A.rb2[l * HH + n] + hreg[l];
#pragma unroll
            for (int g = 0; g < 16; g++) s += g4[(g * 4 + r) * 256 + n];
            f2 = RED(s, s * s);
            mu = f2.x / HH; inv = rsqrtf(f2.y / HH - mu * mu + LN_EPS);
            xr = (s - mu) * inv * A.rln_g[l * HH + n] + A.rln_b[l * HH + n] + xr;
        }

        // ---- output head ----
        yT[n * 4 + r] = xr;
        if (n < 128) yT[(256 + n) * 4 + r] = skv[r * 128 + n];
        __syncthreads();
        matvecR<384, 128, 32>(A.o1w, yT, g4, tid);
        __syncthreads();
        float hs = 0.f;
        if (tid < 512) {
            int m = tid & 127, r2 = tid >> 7;
            hs = A.ob1[m];
#pragma unroll
            for (int g = 0; g < 32; g++) hs += g4[(g * 4 + r2) * 128 + m];
        }
        float2 f2o = REDH(hs, hs * hs);
        float muo = f2o.x / 128.f;
        float invo = rsqrtf(f2o.y / 128.f - muo * muo + LN_EPS);
        float contrib = 0.f;
        if (tid < 512) {
            int m = tid & 127;
            contrib = relu((hs - muo) * invo * A.oln_g[m] + A.oln_b[m]) * A.ow2[m];
        }
        f2o = REDH(contrib, 0.f);
        if (tid < 512 && (tid & 127) == 0) {
            int r2 = tid >> 7;
            A.out[(4 * blk + r2) * TT + t] = f2o.x + A.ob2[0];
        }
        __syncthreads();   // protect xtT / g4 / yT for next step
    }
}

// ---------------- launch ----------------

extern "C" void kernel_launch(void* const* d_in, const int* in_sizes, int n_in,
                              void* d_out, int out_size, void* d_ws, size_t ws_size,
                              hipStream_t stream) {
    Args A;
    A.params     = (const float*)d_in[0];
    A.disp       = (const float*)d_in[1];
    A.ew         = (const float*)d_in[2];
    A.embed_b    = (const float*)d_in[3];
    A.embed_g    = (const float*)d_in[4];
    A.embed_beta = (const float*)d_in[5];
    A.sw         = (const float*)d_in[6];
    A.skip_b     = (const float*)d_in[7];
    A.gw         = (const float*)d_in[8];
    A.gates_b    = (const float*)d_in[9];
    A.inln_g     = (const float*)d_in[10];
    A.inln_b     = (const float*)d_in[11];
    A.hln_g      = (const float*)d_in[12];
    A.hln_b      = (const float*)d_in[13];
    A.sln_g      = (const float*)d_in[14];
    A.sln_b      = (const float*)d_in[15];
    A.a1w        = (const float*)d_in[16];
    A.ab1        = (const float*)d_in[17];
    A.aw2        = (const float*)d_in[18];
    A.ab2        = (const float*)d_in[19];
    A.r1w        = (const float*)d_in[20];
    A.rb1        = (const float*)d_in[21];
    A.r2w        = (const float*)d_in[22];
    A.rb2        = (const float*)d_in[23];
    A.rln_g      = (const float*)d_in[24];
    A.rln_b      = (const float*)d_in[25];
    A.o1w        = (const float*)d_in[26];
    A.ob1        = (const float*)d_in[27];
    A.oln_g      = (const float*)d_in[28];
    A.oln_b      = (const float*)d_in[29];
    A.ow2        = (const float*)d_in[30];
    A.ob2        = (const float*)d_in[31];
    A.out        = (float*)d_out;

    xlstm_kernel<<<32, NTH, 0, stream>>>(A);
}